// Round 6
// baseline (282.371 us; speedup 1.0000x reference)
//
#include <hip/hip_runtime.h>

// FlashMHA: B=2, SQ=SK=2048, E=1024, H=16, D=64.  bf16 MFMA, fp32 accum.
//   convert_all: fp32->bf16; biasc = (mask? bias*log2e : -1e30)
//   gemm_qkv: 768 blocks: y<8 -> Qb=(tgt@Wq^T+bq)*0.125*log2e;
//             y>=8 -> Kb[b,h,s,64] + VTb[b,h,64,s]
//   attn_kernel: static-max flash attn, split-K x2, 32 q-rows/wave.
//                R6: K/V fragments loaded DIRECTLY from global (L1/L2-resident,
//                512KB/XCD under bh-swizzle) — no K/V LDS staging, no barriers.
//                LDS holds only the P round-trip (pitch-72 XOR swizzle; pitch
//                64 was the R3 regression: row drops out of bank index).
//   combine: ctx = (p0+p1)/(l0+l1)  -> bf16
//   gemm_out: 128x64 tiles, grid(32,16)=512 (2 blocks/CU; grid 256 left the
//             barrier drain exposed at 1 block/CU)

using bf16   = __bf16;
using bf16x8 = __attribute__((ext_vector_type(8))) __bf16;
using bf16x4 = __attribute__((ext_vector_type(4))) __bf16;
using f32x4  = __attribute__((ext_vector_type(4))) float;

#define MFMA16x16x32(a, b, c) __builtin_amdgcn_mfma_f32_16x16x32_bf16(a, b, c, 0, 0, 0)

constexpr float LOG2E = 1.4426950408889634f;

__device__ __forceinline__ void gld16(const void* g, void* l) {
  __builtin_amdgcn_global_load_lds(
      (const __attribute__((address_space(1))) unsigned int*)g,
      (__attribute__((address_space(3))) unsigned int*)l, 16, 0, 0);
}

__device__ inline bf16x4 cvt4(float4 v) {
  bf16x4 o;
  o[0] = (bf16)v.x; o[1] = (bf16)v.y; o[2] = (bf16)v.z; o[3] = (bf16)v.w;
  return o;
}

// ---------------------------------------------------------------- convert ---
__global__ __launch_bounds__(256) void convert_all(
    const float4* __restrict__ tgt, const float4* __restrict__ mem,
    const float4* __restrict__ wq,  const float4* __restrict__ wkv,
    const float4* __restrict__ ow,  const float4* __restrict__ bias,
    const int4*   __restrict__ mask,
    bf16x4* __restrict__ tgt_b, bf16x4* __restrict__ mem_b,
    bf16x4* __restrict__ wq_b,  bf16x4* __restrict__ wkv_b,
    bf16x4* __restrict__ ow_b,  float4* __restrict__ biasc)
{
  long i = (long)blockIdx.x * 256 + threadIdx.x;   // float4 index
  const long T0 = 1048576;            // tgt
  const long T1 = T0 + 1048576;       // mem
  const long T2 = T1 + 262144;        // Wq
  const long T3 = T2 + 524288;        // Wkv
  const long T4 = T3 + 262144;        // out_w
  const long T5 = T4 + 1024;          // bias/mask
  if (i < T0)      { tgt_b[i]      = cvt4(tgt[i]); }
  else if (i < T1) { mem_b[i - T0] = cvt4(mem[i - T0]); }
  else if (i < T2) { wq_b[i - T1]  = cvt4(wq[i - T1]); }
  else if (i < T3) { wkv_b[i - T2] = cvt4(wkv[i - T2]); }
  else if (i < T4) { ow_b[i - T3]  = cvt4(ow[i - T3]); }
  else if (i < T5) {
    long j = i - T4;
    float4 bv = bias[j];
    int4   mv = mask[j];
    float4 o;
    o.x = mv.x ? bv.x * LOG2E : -1e30f;
    o.y = mv.y ? bv.y * LOG2E : -1e30f;
    o.z = mv.z ? bv.z * LOG2E : -1e30f;
    o.w = mv.w ? bv.w * LOG2E : -1e30f;
    biasc[j] = o;
  }
}

// ----------------------------------------------------- merged Q + KV GEMM ---
__global__ __launch_bounds__(256) void gemm_qkv(
    const bf16* __restrict__ tgt_b, const bf16* __restrict__ mem_b,
    const bf16* __restrict__ wq_b,  const bf16* __restrict__ wkv_b,
    const float* __restrict__ Wq_bias, const float* __restrict__ Wkv_bias,
    bf16* __restrict__ Qb, bf16* __restrict__ Kb, bf16* __restrict__ VTb)
{
  const int tid  = threadIdx.x;
  const int wave = tid >> 6;
  const int lane = tid & 63;
  const int quad = lane >> 4;
  const int l16  = lane & 15;
  const bool isQ = blockIdx.y < 8;
  const bf16*  A    = isQ ? tgt_b : mem_b;
  const bf16*  B    = isQ ? wq_b  : wkv_b;
  const float* bias = isQ ? Wq_bias : Wkv_bias;
  const int m0 = blockIdx.x * 128;
  const int n0 = (isQ ? blockIdx.y : blockIdx.y - 8) * 128;
  const int wm = (wave & 1) * 64;
  const int wn = (wave >> 1) * 64;
  constexpr int K = 1024;

  __shared__ bf16 As[128][32];    // unpadded: required by global_load_lds
  __shared__ bf16 Bs[128][32];

  f32x4 acc[4][4] = {};

  const int srow = lane >> 2;
  const int scol = (lane & 3) * 8;
  const bf16* gA = A + (size_t)(m0 + wave * 16 + srow) * K + scol;
  const bf16* gB = B + (size_t)(n0 + wave * 16 + srow) * K + scol;
  bf16* lA = &As[wave * 16][0];
  bf16* lB = &Bs[wave * 16][0];

  for (int k0 = 0; k0 < K; k0 += 32) {
    __syncthreads();
    gld16(gA + k0, lA);
    gld16(gA + (size_t)64 * K + k0, lA + 64 * 32);
    gld16(gB + k0, lB);
    gld16(gB + (size_t)64 * K + k0, lB + 64 * 32);
    __syncthreads();

    bf16x8 af[4], bfr[4];
#pragma unroll
    for (int i = 0; i < 4; i++)
      af[i] = *(const bf16x8*)(&As[wm + i * 16 + l16][quad * 8]);
#pragma unroll
    for (int j = 0; j < 4; j++)
      bfr[j] = *(const bf16x8*)(&Bs[wn + j * 16 + l16][quad * 8]);
#pragma unroll
    for (int i = 0; i < 4; i++)
#pragma unroll
      for (int j = 0; j < 4; j++)
        acc[i][j] = MFMA16x16x32(af[i], bfr[j], acc[i][j]);
  }

  const float qscale = 0.125f * LOG2E;
#pragma unroll
  for (int i = 0; i < 4; i++) {
    const int row = m0 + wm + i * 16 + quad * 4;
#pragma unroll
    for (int j = 0; j < 4; j++) {
      const int col = n0 + wn + j * 16 + l16;
      const float bv = bias[col];
      if (isQ) {
#pragma unroll
        for (int r = 0; r < 4; r++)
          Qb[(size_t)(row + r) * 1024 + col] = (bf16)((acc[i][j][r] + bv) * qscale);
      } else {
        const int b = row >> 11, s = row & 2047;
        if (col < 1024) {
          const int hh = col >> 6, dd = col & 63;
          bf16* kp = Kb + ((((size_t)b * 16 + hh) * 2048 + s) * 64 + dd);
#pragma unroll
          for (int r = 0; r < 4; r++) kp[(size_t)r * 64] = (bf16)(acc[i][j][r] + bv);
        } else {
          const int vh = (col - 1024) >> 6, vd = (col - 1024) & 63;
          bf16x4 pk;
#pragma unroll
          for (int r = 0; r < 4; r++) pk[r] = (bf16)(acc[i][j][r] + bv);
          *(bf16x4*)(VTb + (((size_t)b * 16 + vh) * 64 + vd) * 2048 + s) = pk;
        }
      }
    }
  }
}

// --------------------------------------------------------------- out GEMM ---
// 128(M) x 64(N) tiles, grid (32,16) = 512 blocks = 2 blocks/CU.
__global__ __launch_bounds__(256) void gemm_out(
    const bf16* __restrict__ A, const bf16* __restrict__ B,
    const float* __restrict__ bias, float* __restrict__ C)
{
  const int tid  = threadIdx.x;
  const int wave = tid >> 6;
  const int lane = tid & 63;
  const int quad = lane >> 4;
  const int l16  = lane & 15;
  const int m0 = blockIdx.x * 128;
  const int n0 = blockIdx.y * 64;
  const int wm = (wave & 1) * 64;
  const int wn = (wave >> 1) * 32;
  constexpr int K = 1024, N = 1024;

  __shared__ bf16 As[128][32];
  __shared__ bf16 Bs[64][32];

  f32x4 acc[4][2] = {};

  const int srow = lane >> 2;
  const int scol = (lane & 3) * 8;
  const bf16* gA = A + (size_t)(m0 + wave * 16 + srow) * K + scol;
  const bf16* gB = B + (size_t)(n0 + (wave & 3) * 16 + srow) * K + scol;
  bf16* lA = &As[wave * 16][0];
  bf16* lB = &Bs[(wave & 3) * 16][0];

  for (int k0 = 0; k0 < K; k0 += 32) {
    __syncthreads();
    gld16(gA + k0, lA);
    gld16(gA + (size_t)64 * K + k0, lA + 64 * 32);
    gld16(gB + k0, lB);
    __syncthreads();

    bf16x8 af[4], bfr[2];
#pragma unroll
    for (int i = 0; i < 4; i++)
      af[i] = *(const bf16x8*)(&As[wm + i * 16 + l16][quad * 8]);
#pragma unroll
    for (int j = 0; j < 2; j++)
      bfr[j] = *(const bf16x8*)(&Bs[wn + j * 16 + l16][quad * 8]);
#pragma unroll
    for (int i = 0; i < 4; i++)
#pragma unroll
      for (int j = 0; j < 2; j++)
        acc[i][j] = MFMA16x16x32(af[i], bfr[j], acc[i][j]);
  }

#pragma unroll
  for (int i = 0; i < 4; i++) {
    const int row = m0 + wm + i * 16 + quad * 4;
#pragma unroll
    for (int j = 0; j < 2; j++) {
      const int col = n0 + wn + j * 16 + l16;
      const float bv = bias[col];
#pragma unroll
      for (int r = 0; r < 4; r++)
        C[(size_t)(row + r) * N + col] = acc[i][j][r] + bv;
    }
  }
}

// -------------------------------------------------------------- attention ---
// Split-K partials; block = (bh, qtile, shalf); 4 waves x 32 q-rows.
// K/V fragments direct from global (no LDS staging, NO barriers).
// LDS = P round-trip only (pitch 72, XOR swizzle — verified R5).
__global__ __launch_bounds__(256, 4) void attn_kernel(
    const bf16* __restrict__ Qb, const bf16* __restrict__ Kb,
    const bf16* __restrict__ VTb, const float* __restrict__ biasc,
    bf16* __restrict__ Pp, float* __restrict__ Ls)
{
  const int tid  = threadIdx.x;
  const int wave = tid >> 6;
  const int lane = tid & 63;
  const int quad = lane >> 4;
  const int l16  = lane & 15;
  const int blk   = blockIdx.x;                   // 0..1023
  const int bh    = (blk & 7) * 4 + (blk >> 8);   // same bh -> same XCD
  const int qtile = (blk >> 3) & 15;
  const int shalf = (blk >> 7) & 1;
  const int bi    = bh >> 4;
  const int h     = bh & 15;

  __shared__ bf16 Ps[4][32][72];             // per-wave P, XOR-swizzled, pitch 72

  const int qrow0 = qtile * 128 + wave * 32;
  bf16x8 aq[2][2];
#pragma unroll
  for (int t = 0; t < 2; t++)
#pragma unroll
    for (int k = 0; k < 2; k++)
      aq[t][k] = *(const bf16x8*)(Qb + (size_t)(bi * 2048 + qrow0 + t * 16 + l16) * 1024
                                  + h * 64 + k * 32 + quad * 8);

  bf16x8 ones;
#pragma unroll
  for (int j = 0; j < 8; j++) ones[j] = (bf16)1.0f;

  f32x4 acc[2][4] = {};
  f32x4 lacc[2]   = {};

  const bf16* kbase = Kb  + (size_t)bh * 2048 * 64;
  const bf16* vbase = VTb + (size_t)bh * 64 * 2048;
  const float* bptr = biasc + bi * 2048;

  const int c2 = l16 >> 2;        // P read-swizzle key

  const int sbeg = shalf * 1024;
  for (int s0 = sbeg; s0 < sbeg + 1024; s0 += 64) {
    // hoist all K fragments for this chunk: 8 loads in flight
    bf16x8 kb0[4], kb1[4];
#pragma unroll
    for (int c = 0; c < 4; c++) {
      const bf16* kp = kbase + (size_t)(s0 + c * 16 + l16) * 64 + quad * 8;
      kb0[c] = *(const bf16x8*)kp;
      kb1[c] = *(const bf16x8*)(kp + 32);
    }
    float bv[4];
#pragma unroll
    for (int c = 0; c < 4; c++) bv[c] = bptr[s0 + c * 16 + l16];

    // S = Q K^T, softmax (static max, log2 domain), P -> swizzled LDS
#pragma unroll
    for (int c = 0; c < 4; c++) {
      const int csw = ((c * 2 + (l16 >> 3)) ^ quad) * 8 + (l16 & 7);
#pragma unroll
      for (int t = 0; t < 2; t++) {
        f32x4 s = {};
        s = MFMA16x16x32(aq[t][0], kb0[c], s);
        s = MFMA16x16x32(aq[t][1], kb1[c], s);
#pragma unroll
        for (int r = 0; r < 4; r++) {
          float p = __builtin_amdgcn_exp2f(s[r] + bv[c]);
          Ps[wave][t * 16 + quad * 4 + r][csw] = (bf16)p;
        }
      }
    }

    // V fragments direct from global (reused by both q-tiles)
    bf16x8 vb0[4], vb1[4];
#pragma unroll
    for (int db = 0; db < 4; db++) {
      const bf16* vp = vbase + (size_t)(db * 16 + l16) * 2048 + s0 + quad * 8;
      vb0[db] = *(const bf16x8*)vp;
      vb1[db] = *(const bf16x8*)(vp + 32);
    }
#pragma unroll
    for (int t = 0; t < 2; t++) {
      bf16x8 ap0 = *(const bf16x8*)(&Ps[wave][t * 16 + l16][(quad ^ c2) * 8]);
      bf16x8 ap1 = *(const bf16x8*)(&Ps[wave][t * 16 + l16][32 + (quad ^ c2) * 8]);
      lacc[t] = MFMA16x16x32(ap0, ones, lacc[t]);
      lacc[t] = MFMA16x16x32(ap1, ones, lacc[t]);
#pragma unroll
      for (int db = 0; db < 4; db++) {
        acc[t][db] = MFMA16x16x32(ap0, vb0[db], acc[t][db]);
        acc[t][db] = MFMA16x16x32(ap1, vb1[db], acc[t][db]);
      }
    }
  }

  // store raw partials (no normalization here)
#pragma unroll
  for (int t = 0; t < 2; t++) {
    const int rowb = bi * 2048 + qrow0 + t * 16 + quad * 4;
#pragma unroll
    for (int r = 0; r < 4; r++)
      if (l16 == 0)
        Ls[shalf * 65536 + (rowb + r) * 16 + h] = lacc[t][r];
#pragma unroll
    for (int db = 0; db < 4; db++)
#pragma unroll
      for (int r = 0; r < 4; r++)
        Pp[(size_t)shalf * 4194304 + (size_t)(rowb + r) * 1024 + h * 64 + db * 16 + l16]
            = (bf16)acc[t][db][r];
  }
}

// ---------------------------------------------------------------- combine ---
__global__ __launch_bounds__(256) void combine_kernel(
    const bf16* __restrict__ Pp, const float* __restrict__ Ls,
    bf16* __restrict__ ctx)
{
  const int t   = blockIdx.x * 256 + threadIdx.x;   // 0..524287
  const int row = t >> 7;
  const int g   = t & 127;
  const int h   = g >> 3;
  const bf16x8 p0 = *(const bf16x8*)(Pp + (size_t)row * 1024 + g * 8);
  const bf16x8 p1 = *(const bf16x8*)(Pp + 4194304 + (size_t)row * 1024 + g * 8);
  const float inv = 1.0f / (Ls[row * 16 + h] + Ls[65536 + row * 16 + h]);
  bf16x8 o;
#pragma unroll
  for (int j = 0; j < 8; j++)
    o[j] = (bf16)(((float)p0[j] + (float)p1[j]) * inv);
  *(bf16x8*)(ctx + (size_t)row * 1024 + g * 8) = o;
}

// ----------------------------------------------------------------- launch ---
extern "C" void kernel_launch(void* const* d_in, const int* in_sizes, int n_in,
                              void* d_out, int out_size, void* d_ws, size_t ws_size,
                              hipStream_t stream)
{
  const float* tgt       = (const float*)d_in[0];
  const float* mem       = (const float*)d_in[1];
  const float* attn_bias = (const float*)d_in[2];
  const int*   mask      = (const int*)d_in[3];
  const float* Wq_b      = (const float*)d_in[5];
  const float* Wkv_b     = (const float*)d_in[7];
  const float* out_b     = (const float*)d_in[9];
  float* out = (float*)d_out;

  bf16*  base  = (bf16*)d_ws;
  bf16*  tgt_b = base;
  bf16*  mem_b = tgt_b + 4194304;
  bf16*  wq_b  = mem_b + 4194304;
  bf16*  wkv_b = wq_b + 1048576;
  bf16*  ow_b  = wkv_b + 2097152;
  float* biasc = (float*)(ow_b + 1048576);
  bf16*  Qb    = (bf16*)(biasc + 4096);
  bf16*  Kb    = Qb + 4194304;
  bf16*  VTb   = Kb + 4194304;
  // overlays (regions dead by the time these are written):
  bf16*  Pp    = base;            // partial ctx [2][4096][1024] over tgt_b+mem_b
  float* Ls    = (float*)wq_b;    // partial lsum [2][4096][16] over wq_b
  bf16*  ctxb  = Qb;              // combined ctx over Qb (dead after attn)

  convert_all<<<12292, 256, 0, stream>>>(
      (const float4*)tgt, (const float4*)mem, (const float4*)d_in[4],
      (const float4*)d_in[6], (const float4*)d_in[8], (const float4*)attn_bias,
      (const int4*)mask,
      (bf16x4*)tgt_b, (bf16x4*)mem_b, (bf16x4*)wq_b, (bf16x4*)wkv_b,
      (bf16x4*)ow_b, (float4*)biasc);

  gemm_qkv<<<dim3(32, 24), 256, 0, stream>>>(
      tgt_b, mem_b, wq_b, wkv_b, Wq_b, Wkv_b, Qb, Kb, VTb);
  attn_kernel<<<1024, 256, 0, stream>>>(Qb, Kb, VTb, biasc, Pp, Ls);
  combine_kernel<<<2048, 256, 0, stream>>>(Pp, Ls, ctxb);
  gemm_out<<<dim3(32, 16), 256, 0, stream>>>(ctxb, ow_b, out_b, out);
}

// Round 7
// 212.479 us; speedup vs baseline: 1.3289x; 1.3289x over previous
//
#include <hip/hip_runtime.h>

// FlashMHA: B=2, SQ=SK=2048, E=1024, H=16, D=64.  bf16 MFMA, fp32 accum.
//   convert_all: fp32->bf16; biasc = (mask? bias*log2e : -1e30)
//   gemm_qkv: 768 blocks: y<8 -> Qb=(tgt@Wq^T+bq)*0.125*log2e;
//             y>=8 -> Kb[b,h,s,64] + VTb[b,h,64,s]
//   attn_kernel: R5 structure (LDS-staged K/V — R6's direct-global frags were
//                VMEM-latency-bound, 131us) + R7: cross-chunk VGPR prefetch:
//                next chunk's K/V global loads issue before compute of the
//                current chunk, hiding ~300-900cyc load latency under ~400cyc
//                of MFMA/exp work.  P-tile pitch 72 XOR swizzle (verified R5;
//                pitch 64 = R3 regression).
//   combine: ctx = (p0+p1)/(l0+l1)  -> bf16
//   gemm_out: 128x64 tiles, grid(32,16)=512 (2 blocks/CU)

using bf16   = __bf16;
using bf16x8 = __attribute__((ext_vector_type(8))) __bf16;
using bf16x4 = __attribute__((ext_vector_type(4))) __bf16;
using f32x4  = __attribute__((ext_vector_type(4))) float;

#define MFMA16x16x32(a, b, c) __builtin_amdgcn_mfma_f32_16x16x32_bf16(a, b, c, 0, 0, 0)

constexpr float LOG2E = 1.4426950408889634f;

__device__ __forceinline__ void gld16(const void* g, void* l) {
  __builtin_amdgcn_global_load_lds(
      (const __attribute__((address_space(1))) unsigned int*)g,
      (__attribute__((address_space(3))) unsigned int*)l, 16, 0, 0);
}

__device__ inline bf16x4 cvt4(float4 v) {
  bf16x4 o;
  o[0] = (bf16)v.x; o[1] = (bf16)v.y; o[2] = (bf16)v.z; o[3] = (bf16)v.w;
  return o;
}

// ---------------------------------------------------------------- convert ---
__global__ __launch_bounds__(256) void convert_all(
    const float4* __restrict__ tgt, const float4* __restrict__ mem,
    const float4* __restrict__ wq,  const float4* __restrict__ wkv,
    const float4* __restrict__ ow,  const float4* __restrict__ bias,
    const int4*   __restrict__ mask,
    bf16x4* __restrict__ tgt_b, bf16x4* __restrict__ mem_b,
    bf16x4* __restrict__ wq_b,  bf16x4* __restrict__ wkv_b,
    bf16x4* __restrict__ ow_b,  float4* __restrict__ biasc)
{
  long i = (long)blockIdx.x * 256 + threadIdx.x;   // float4 index
  const long T0 = 1048576;            // tgt
  const long T1 = T0 + 1048576;       // mem
  const long T2 = T1 + 262144;        // Wq
  const long T3 = T2 + 524288;        // Wkv
  const long T4 = T3 + 262144;        // out_w
  const long T5 = T4 + 1024;          // bias/mask
  if (i < T0)      { tgt_b[i]      = cvt4(tgt[i]); }
  else if (i < T1) { mem_b[i - T0] = cvt4(mem[i - T0]); }
  else if (i < T2) { wq_b[i - T1]  = cvt4(wq[i - T1]); }
  else if (i < T3) { wkv_b[i - T2] = cvt4(wkv[i - T2]); }
  else if (i < T4) { ow_b[i - T3]  = cvt4(ow[i - T3]); }
  else if (i < T5) {
    long j = i - T4;
    float4 bv = bias[j];
    int4   mv = mask[j];
    float4 o;
    o.x = mv.x ? bv.x * LOG2E : -1e30f;
    o.y = mv.y ? bv.y * LOG2E : -1e30f;
    o.z = mv.z ? bv.z * LOG2E : -1e30f;
    o.w = mv.w ? bv.w * LOG2E : -1e30f;
    biasc[j] = o;
  }
}

// ----------------------------------------------------- merged Q + KV GEMM ---
__global__ __launch_bounds__(256) void gemm_qkv(
    const bf16* __restrict__ tgt_b, const bf16* __restrict__ mem_b,
    const bf16* __restrict__ wq_b,  const bf16* __restrict__ wkv_b,
    const float* __restrict__ Wq_bias, const float* __restrict__ Wkv_bias,
    bf16* __restrict__ Qb, bf16* __restrict__ Kb, bf16* __restrict__ VTb)
{
  const int tid  = threadIdx.x;
  const int wave = tid >> 6;
  const int lane = tid & 63;
  const int quad = lane >> 4;
  const int l16  = lane & 15;
  const bool isQ = blockIdx.y < 8;
  const bf16*  A    = isQ ? tgt_b : mem_b;
  const bf16*  B    = isQ ? wq_b  : wkv_b;
  const float* bias = isQ ? Wq_bias : Wkv_bias;
  const int m0 = blockIdx.x * 128;
  const int n0 = (isQ ? blockIdx.y : blockIdx.y - 8) * 128;
  const int wm = (wave & 1) * 64;
  const int wn = (wave >> 1) * 64;
  constexpr int K = 1024;

  __shared__ bf16 As[128][32];    // unpadded: required by global_load_lds
  __shared__ bf16 Bs[128][32];

  f32x4 acc[4][4] = {};

  const int srow = lane >> 2;
  const int scol = (lane & 3) * 8;
  const bf16* gA = A + (size_t)(m0 + wave * 16 + srow) * K + scol;
  const bf16* gB = B + (size_t)(n0 + wave * 16 + srow) * K + scol;
  bf16* lA = &As[wave * 16][0];
  bf16* lB = &Bs[wave * 16][0];

  for (int k0 = 0; k0 < K; k0 += 32) {
    __syncthreads();
    gld16(gA + k0, lA);
    gld16(gA + (size_t)64 * K + k0, lA + 64 * 32);
    gld16(gB + k0, lB);
    gld16(gB + (size_t)64 * K + k0, lB + 64 * 32);
    __syncthreads();

    bf16x8 af[4], bfr[4];
#pragma unroll
    for (int i = 0; i < 4; i++)
      af[i] = *(const bf16x8*)(&As[wm + i * 16 + l16][quad * 8]);
#pragma unroll
    for (int j = 0; j < 4; j++)
      bfr[j] = *(const bf16x8*)(&Bs[wn + j * 16 + l16][quad * 8]);
#pragma unroll
    for (int i = 0; i < 4; i++)
#pragma unroll
      for (int j = 0; j < 4; j++)
        acc[i][j] = MFMA16x16x32(af[i], bfr[j], acc[i][j]);
  }

  const float qscale = 0.125f * LOG2E;
#pragma unroll
  for (int i = 0; i < 4; i++) {
    const int row = m0 + wm + i * 16 + quad * 4;
#pragma unroll
    for (int j = 0; j < 4; j++) {
      const int col = n0 + wn + j * 16 + l16;
      const float bv = bias[col];
      if (isQ) {
#pragma unroll
        for (int r = 0; r < 4; r++)
          Qb[(size_t)(row + r) * 1024 + col] = (bf16)((acc[i][j][r] + bv) * qscale);
      } else {
        const int b = row >> 11, s = row & 2047;
        if (col < 1024) {
          const int hh = col >> 6, dd = col & 63;
          bf16* kp = Kb + ((((size_t)b * 16 + hh) * 2048 + s) * 64 + dd);
#pragma unroll
          for (int r = 0; r < 4; r++) kp[(size_t)r * 64] = (bf16)(acc[i][j][r] + bv);
        } else {
          const int vh = (col - 1024) >> 6, vd = (col - 1024) & 63;
          bf16x4 pk;
#pragma unroll
          for (int r = 0; r < 4; r++) pk[r] = (bf16)(acc[i][j][r] + bv);
          *(bf16x4*)(VTb + (((size_t)b * 16 + vh) * 64 + vd) * 2048 + s) = pk;
        }
      }
    }
  }
}

// --------------------------------------------------------------- out GEMM ---
// 128(M) x 64(N) tiles, grid (32,16) = 512 blocks = 2 blocks/CU.
__global__ __launch_bounds__(256) void gemm_out(
    const bf16* __restrict__ A, const bf16* __restrict__ B,
    const float* __restrict__ bias, float* __restrict__ C)
{
  const int tid  = threadIdx.x;
  const int wave = tid >> 6;
  const int lane = tid & 63;
  const int quad = lane >> 4;
  const int l16  = lane & 15;
  const int m0 = blockIdx.x * 128;
  const int n0 = blockIdx.y * 64;
  const int wm = (wave & 1) * 64;
  const int wn = (wave >> 1) * 32;
  constexpr int K = 1024, N = 1024;

  __shared__ bf16 As[128][32];
  __shared__ bf16 Bs[64][32];

  f32x4 acc[4][2] = {};

  const int srow = lane >> 2;
  const int scol = (lane & 3) * 8;
  const bf16* gA = A + (size_t)(m0 + wave * 16 + srow) * K + scol;
  const bf16* gB = B + (size_t)(n0 + (wave & 3) * 16 + srow) * K + scol;
  bf16* lA = &As[wave * 16][0];
  bf16* lB = &Bs[(wave & 3) * 16][0];

  for (int k0 = 0; k0 < K; k0 += 32) {
    __syncthreads();
    gld16(gA + k0, lA);
    gld16(gA + (size_t)64 * K + k0, lA + 64 * 32);
    gld16(gB + k0, lB);
    __syncthreads();

    bf16x8 af[4], bfr[2];
#pragma unroll
    for (int i = 0; i < 4; i++)
      af[i] = *(const bf16x8*)(&As[wm + i * 16 + l16][quad * 8]);
#pragma unroll
    for (int j = 0; j < 2; j++)
      bfr[j] = *(const bf16x8*)(&Bs[wn + j * 16 + l16][quad * 8]);
#pragma unroll
    for (int i = 0; i < 4; i++)
#pragma unroll
      for (int j = 0; j < 2; j++)
        acc[i][j] = MFMA16x16x32(af[i], bfr[j], acc[i][j]);
  }

#pragma unroll
  for (int i = 0; i < 4; i++) {
    const int row = m0 + wm + i * 16 + quad * 4;
#pragma unroll
    for (int j = 0; j < 2; j++) {
      const int col = n0 + wn + j * 16 + l16;
      const float bv = bias[col];
#pragma unroll
      for (int r = 0; r < 4; r++)
        C[(size_t)(row + r) * N + col] = acc[i][j][r] + bv;
    }
  }
}

// -------------------------------------------------------------- attention ---
// Split-K partials; block = (bh, qtile, shalf); 4 waves x 32 q-rows.
// R5 LDS staging + R7 cross-chunk VGPR prefetch: chunk n+1's global loads
// issue before chunk n's compute, so load latency hides under MFMA/exp work.
__global__ __launch_bounds__(256, 4) void attn_kernel(
    const bf16* __restrict__ Qb, const bf16* __restrict__ Kb,
    const bf16* __restrict__ VTb, const float* __restrict__ biasc,
    bf16* __restrict__ Pp, float* __restrict__ Ls)
{
  const int tid  = threadIdx.x;
  const int wave = tid >> 6;
  const int lane = tid & 63;
  const int quad = lane >> 4;
  const int l16  = lane & 15;
  const int blk   = blockIdx.x;                   // 0..1023
  const int bh    = (blk & 7) * 4 + (blk >> 8);   // same bh -> same XCD
  const int qtile = (blk >> 3) & 15;
  const int shalf = (blk >> 7) & 1;
  const int bi    = bh >> 4;
  const int h     = bh & 15;

  __shared__ bf16 Ks[64][72];                // [s][d]  pitch 144B
  __shared__ bf16 Vs[64][72];                // [d][s]
  __shared__ bf16 Ps[4][32][72];             // per-wave P, XOR-swizzled, pitch 72

  const int qrow0 = qtile * 128 + wave * 32;
  bf16x8 aq[2][2];
#pragma unroll
  for (int t = 0; t < 2; t++)
#pragma unroll
    for (int k = 0; k < 2; k++)
      aq[t][k] = *(const bf16x8*)(Qb + (size_t)(bi * 2048 + qrow0 + t * 16 + l16) * 1024
                                  + h * 64 + k * 32 + quad * 8);

  bf16x8 ones;
#pragma unroll
  for (int j = 0; j < 8; j++) ones[j] = (bf16)1.0f;

  f32x4 acc[2][4] = {};
  f32x4 lacc[2]   = {};

  const bf16* kbase = Kb  + (size_t)bh * 2048 * 64;
  const bf16* vbase = VTb + (size_t)bh * 64 * 2048;
  const float* bptr = biasc + bi * 2048;

  const int r8 = tid >> 3;        // 0..31
  const int c8 = (tid & 7) * 8;   // 0..56
  const int c2 = l16 >> 2;        // P read-swizzle key

  const int sbeg = shalf * 1024;

  // prefetch chunk 0 into registers
  bf16x8 pk0, pk1, pv0, pv1;
  float  pbv[4];
  {
    const int s0 = sbeg;
    pk0 = *(const bf16x8*)(kbase + (size_t)(s0 + r8) * 64 + c8);
    pk1 = *(const bf16x8*)(kbase + (size_t)(s0 + 32 + r8) * 64 + c8);
    pv0 = *(const bf16x8*)(vbase + (size_t)r8 * 2048 + s0 + c8);
    pv1 = *(const bf16x8*)(vbase + (size_t)(r8 + 32) * 2048 + s0 + c8);
#pragma unroll
    for (int c = 0; c < 4; c++) pbv[c] = bptr[s0 + c * 16 + l16];
  }

  for (int ci = 0; ci < 16; ci++) {
    __syncthreads();                 // previous chunk's LDS reads done
    *(bf16x8*)(&Ks[r8][c8])      = pk0;
    *(bf16x8*)(&Ks[r8 + 32][c8]) = pk1;
    *(bf16x8*)(&Vs[r8][c8])      = pv0;
    *(bf16x8*)(&Vs[r8 + 32][c8]) = pv1;
    float bv[4];
#pragma unroll
    for (int c = 0; c < 4; c++) bv[c] = pbv[c];

    // issue next chunk's loads NOW (wrap on last iter -> harmless L1 hit)
    {
      int sn = sbeg + ((ci + 1) & 15) * 64;
      pk0 = *(const bf16x8*)(kbase + (size_t)(sn + r8) * 64 + c8);
      pk1 = *(const bf16x8*)(kbase + (size_t)(sn + 32 + r8) * 64 + c8);
      pv0 = *(const bf16x8*)(vbase + (size_t)r8 * 2048 + sn + c8);
      pv1 = *(const bf16x8*)(vbase + (size_t)(r8 + 32) * 2048 + sn + c8);
#pragma unroll
      for (int c = 0; c < 4; c++) pbv[c] = bptr[sn + c * 16 + l16];
    }
    __syncthreads();                 // staging writes visible

    // S = Q K^T, softmax (static max, log2 domain), P -> swizzled LDS
#pragma unroll
    for (int c = 0; c < 4; c++) {
      bf16x8 b0 = *(const bf16x8*)(&Ks[c * 16 + l16][quad * 8]);
      bf16x8 b1 = *(const bf16x8*)(&Ks[c * 16 + l16][32 + quad * 8]);
      const int csw = ((c * 2 + (l16 >> 3)) ^ quad) * 8 + (l16 & 7);
#pragma unroll
      for (int t = 0; t < 2; t++) {
        f32x4 s = {};
        s = MFMA16x16x32(aq[t][0], b0, s);
        s = MFMA16x16x32(aq[t][1], b1, s);
#pragma unroll
        for (int r = 0; r < 4; r++) {
          float p = __builtin_amdgcn_exp2f(s[r] + bv[c]);
          Ps[wave][t * 16 + quad * 4 + r][csw] = (bf16)p;
        }
      }
    }

    // V fragments (hoisted, reused by both q-tiles)
    bf16x8 vb0[4], vb1[4];
#pragma unroll
    for (int db = 0; db < 4; db++) {
      vb0[db] = *(const bf16x8*)(&Vs[db * 16 + l16][quad * 8]);
      vb1[db] = *(const bf16x8*)(&Vs[db * 16 + l16][32 + quad * 8]);
    }
#pragma unroll
    for (int t = 0; t < 2; t++) {
      bf16x8 ap0 = *(const bf16x8*)(&Ps[wave][t * 16 + l16][(quad ^ c2) * 8]);
      bf16x8 ap1 = *(const bf16x8*)(&Ps[wave][t * 16 + l16][32 + (quad ^ c2) * 8]);
      lacc[t] = MFMA16x16x32(ap0, ones, lacc[t]);
      lacc[t] = MFMA16x16x32(ap1, ones, lacc[t]);
#pragma unroll
      for (int db = 0; db < 4; db++) {
        acc[t][db] = MFMA16x16x32(ap0, vb0[db], acc[t][db]);
        acc[t][db] = MFMA16x16x32(ap1, vb1[db], acc[t][db]);
      }
    }
  }

  // store raw partials (no normalization here)
#pragma unroll
  for (int t = 0; t < 2; t++) {
    const int rowb = bi * 2048 + qrow0 + t * 16 + quad * 4;
#pragma unroll
    for (int r = 0; r < 4; r++)
      if (l16 == 0)
        Ls[shalf * 65536 + (rowb + r) * 16 + h] = lacc[t][r];
#pragma unroll
    for (int db = 0; db < 4; db++)
#pragma unroll
      for (int r = 0; r < 4; r++)
        Pp[(size_t)shalf * 4194304 + (size_t)(rowb + r) * 1024 + h * 64 + db * 16 + l16]
            = (bf16)acc[t][db][r];
  }
}

// ---------------------------------------------------------------- combine ---
__global__ __launch_bounds__(256) void combine_kernel(
    const bf16* __restrict__ Pp, const float* __restrict__ Ls,
    bf16* __restrict__ ctx)
{
  const int t   = blockIdx.x * 256 + threadIdx.x;   // 0..524287
  const int row = t >> 7;
  const int g   = t & 127;
  const int h   = g >> 3;
  const bf16x8 p0 = *(const bf16x8*)(Pp + (size_t)row * 1024 + g * 8);
  const bf16x8 p1 = *(const bf16x8*)(Pp + 4194304 + (size_t)row * 1024 + g * 8);
  const float inv = 1.0f / (Ls[row * 16 + h] + Ls[65536 + row * 16 + h]);
  bf16x8 o;
#pragma unroll
  for (int j = 0; j < 8; j++)
    o[j] = (bf16)(((float)p0[j] + (float)p1[j]) * inv);
  *(bf16x8*)(ctx + (size_t)row * 1024 + g * 8) = o;
}

// ----------------------------------------------------------------- launch ---
extern "C" void kernel_launch(void* const* d_in, const int* in_sizes, int n_in,
                              void* d_out, int out_size, void* d_ws, size_t ws_size,
                              hipStream_t stream)
{
  const float* tgt       = (const float*)d_in[0];
  const float* mem       = (const float*)d_in[1];
  const float* attn_bias = (const float*)d_in[2];
  const int*   mask      = (const int*)d_in[3];
  const float* Wq_b      = (const float*)d_in[5];
  const float* Wkv_b     = (const float*)d_in[7];
  const float* out_b     = (const float*)d_in[9];
  float* out = (float*)d_out;

  bf16*  base  = (bf16*)d_ws;
  bf16*  tgt_b = base;
  bf16*  mem_b = tgt_b + 4194304;
  bf16*  wq_b  = mem_b + 4194304;
  bf16*  wkv_b = wq_b + 1048576;
  bf16*  ow_b  = wkv_b + 2097152;
  float* biasc = (float*)(ow_b + 1048576);
  bf16*  Qb    = (bf16*)(biasc + 4096);
  bf16*  Kb    = Qb + 4194304;
  bf16*  VTb   = Kb + 4194304;
  // overlays (regions dead by the time these are written):
  bf16*  Pp    = base;            // partial ctx [2][4096][1024] over tgt_b+mem_b
  float* Ls    = (float*)wq_b;    // partial lsum [2][4096][16] over wq_b
  bf16*  ctxb  = Qb;              // combined ctx over Qb (dead after attn)

  convert_all<<<12292, 256, 0, stream>>>(
      (const float4*)tgt, (const float4*)mem, (const float4*)d_in[4],
      (const float4*)d_in[6], (const float4*)d_in[8], (const float4*)attn_bias,
      (const int4*)mask,
      (bf16x4*)tgt_b, (bf16x4*)mem_b, (bf16x4*)wq_b, (bf16x4*)wkv_b,
      (bf16x4*)ow_b, (float4*)biasc);

  gemm_qkv<<<dim3(32, 24), 256, 0, stream>>>(
      tgt_b, mem_b, wq_b, wkv_b, Wq_b, Wkv_b, Qb, Kb, VTb);
  attn_kernel<<<1024, 256, 0, stream>>>(Qb, Kb, VTb, biasc, Pp, Ls);
  combine_kernel<<<2048, 256, 0, stream>>>(Pp, Ls, ctxb);
  gemm_out<<<dim3(32, 16), 256, 0, stream>>>(ctxb, ow_b, out_b, out);
}